// Round 1
// baseline (9076.632 us; speedup 1.0000x reference)
//
#include <hip/hip_runtime.h>

// LSTM T=32768, D=512, H=20.
// Phase 1: xg[t][80] = x[t] @ W_ih^T + (b_ih + b_hh)   (tiled fp32 GEMM)
// Phase 2: sequential scan, ONE wave, latency-optimized:
//   lanes 0..19  : unit j, gates i (rowA=j)    and f (rowB=20+j)
//   lanes 32..51 : unit j, gates g (rowA=40+j) and o (rowB=60+j)
//   h broadcast via v_readlane -> SGPRs (no LDS round trip, no barriers)
//   unified activation act(x) = C + A*rcp(1 + exp2(B*x)) so one exp2+rcp
//   pass activates sigmoid (lower half) and tanh (upper half) together.
// Phase 3: out[t] = hs[t] @ W_out^T + b_out
//
// d_out layout: [0..T) outputs, [T..T+20) hT, [T+20..T+40) cT
// d_ws layout:  xg (T+16 rows x 80 fp32) then hs (T x 20 fp32)  ~= 13.1 MB

#define TT 32768
#define DD 512
#define HH 20

__device__ __forceinline__ float ex2(float x) {
#if __has_builtin(__builtin_amdgcn_exp2f)
  return __builtin_amdgcn_exp2f(x);
#else
  return exp2f(x);
#endif
}
__device__ __forceinline__ float rcpa(float x) { return __builtin_amdgcn_rcpf(x); }
__device__ __forceinline__ float rlane(float v, int l) {
  return __int_as_float(__builtin_amdgcn_readlane(__float_as_int(v), l));
}

// ---------------- Phase 1: xg GEMM -------------------------------------
// Block: 256 threads, tile 64 t x 80 gates, BK=64, micro-tile 4t x 5g.
__global__ __launch_bounds__(256)
void xg_gemm(const float* __restrict__ x,    // (T, 512)
             const float* __restrict__ Wih,  // (80, 512)
             const float* __restrict__ bih,  // (80)
             const float* __restrict__ bhh,  // (80)
             float* __restrict__ xg)         // (T+16, 80)
{
  __shared__ float xa[64][68];   // +4 pad keeps float4 alignment, shifts banks
  __shared__ float wb[80][68];

  const int tid = threadIdx.x;
  const int t0  = blockIdx.x << 6;          // 64 timesteps per block
  const int tt  = (tid & 15) << 2;          // 0..60
  const int gg  = (tid >> 4) * 5;           // 0..75

  float acc[4][5];
#pragma unroll
  for (int i = 0; i < 4; ++i)
#pragma unroll
    for (int q = 0; q < 5; ++q) acc[i][q] = 0.0f;

  for (int k0 = 0; k0 < DD; k0 += 64) {
    // stage x tile: 64x64 = 1024 float4, 4 per thread
#pragma unroll
    for (int i = 0; i < 4; ++i) {
      int id = tid + (i << 8);
      int r = id >> 4, c4 = (id & 15) << 2;
      *(float4*)&xa[r][c4] = *(const float4*)&x[(size_t)(t0 + r) * DD + k0 + c4];
    }
    // stage W tile: 80x64 = 1280 float4, 5 per thread
#pragma unroll
    for (int i = 0; i < 5; ++i) {
      int id = tid + (i << 8);
      int r = id >> 4, c4 = (id & 15) << 2;
      *(float4*)&wb[r][c4] = *(const float4*)&Wih[(size_t)r * DD + k0 + c4];
    }
    __syncthreads();

#pragma unroll 4
    for (int kk = 0; kk < 64; kk += 4) {
      float4 a[4], b[5];
#pragma unroll
      for (int i = 0; i < 4; ++i) a[i] = *(const float4*)&xa[tt + i][kk];
#pragma unroll
      for (int q = 0; q < 5; ++q) b[q] = *(const float4*)&wb[gg + q][kk];
#pragma unroll
      for (int i = 0; i < 4; ++i)
#pragma unroll
        for (int q = 0; q < 5; ++q) {
          acc[i][q] = fmaf(a[i].x, b[q].x, acc[i][q]);
          acc[i][q] = fmaf(a[i].y, b[q].y, acc[i][q]);
          acc[i][q] = fmaf(a[i].z, b[q].z, acc[i][q]);
          acc[i][q] = fmaf(a[i].w, b[q].w, acc[i][q]);
        }
    }
    __syncthreads();
  }

  float bg[5];
#pragma unroll
  for (int q = 0; q < 5; ++q) bg[q] = bih[gg + q] + bhh[gg + q];
#pragma unroll
  for (int i = 0; i < 4; ++i)
#pragma unroll
    for (int q = 0; q < 5; ++q)
      xg[(size_t)(t0 + tt + i) * 80 + gg + q] = acc[i][q] + bg[q];
}

// ---------------- Phase 2: sequential scan, one wave -------------------
__global__ __launch_bounds__(64, 1)
void lstm_scan(const float* __restrict__ xg,   // (T+16, 80)
               const float* __restrict__ Whh,  // (80, 20)
               const float* __restrict__ h0,   // (20)
               const float* __restrict__ c0,   // (20)
               float* __restrict__ hs,         // (T, 20)
               float* __restrict__ dout)       // d_out base (fp32)
{
  const int lane = threadIdx.x & 63;
  const int half = lane >> 5;              // 0: gates i,f   1: gates g,o
  int jj = lane & 31; if (jj > 19) jj = 19;   // clamp: spare lanes dup unit 19
  const int rowA = half ? (40 + jj) : jj;
  const int rowB = rowA + 20;

  float wA[HH], wB[HH];
#pragma unroll
  for (int k = 0; k < HH; ++k) {
    wA[k] = Whh[rowA * HH + k];
    wB[k] = Whh[rowB * HH + k];
  }

  // unified activation constants: sigmoid lower half, tanh upper half
  const float A0 = half ? -2.0f        : 1.0f;
  const float B0 = half ? 2.88539008f  : -1.44269504f;
  const float C0 = half ? 1.0f         : 0.0f;

  float h = h0[jj];
  float c = c0[jj];

  constexpr int DIST = 8;                  // prefetch ring depth (steps)
  float pA[DIST], pB[DIST];
#pragma unroll
  for (int u = 0; u < DIST; ++u) {
    pA[u] = xg[(size_t)u * 80 + rowA];
    pB[u] = xg[(size_t)u * 80 + rowB];
  }

  for (int tb = 0; tb < TT; tb += DIST) {
#pragma unroll
    for (int u = 0; u < DIST; ++u) {
      const int t = tb + u;
      float gA = pA[u], gB = pB[u];
      // prefetch t+DIST (xg padded to T+16 rows; overrun rows never consumed)
      const float* pn = xg + (size_t)(t + DIST) * 80;
      pA[u] = pn[rowA];
      pB[u] = pn[rowB];

      // mat-vec: h broadcast through SGPRs via readlane (lanes 0..19 hold h)
#pragma unroll
      for (int k = 0; k < HH; ++k) {
        const float hk = rlane(h, k);
        gA = fmaf(hk, wA[k], gA);
        gB = fmaf(hk, wB[k], gB);
      }

      // one trans pass does sigmoid(i)|tanh(g); second does sigmoid(f|o)
      const float vA = fmaf(A0, rcpa(1.0f + ex2(B0 * gA)), C0);
      const float vB = rcpa(1.0f + ex2(-1.44269504f * gB));

      // lower lane j pulls tanh(g_j), sigmoid(o_j) from lane 32+j
      const float tgx = __shfl(vA, (lane & 31) + 32);
      const float sox = __shfl(vB, (lane & 31) + 32);

      c = fmaf(vB, c, vA * tgx);                                   // f*c + i*tg
      const float th = fmaf(-2.0f, rcpa(1.0f + ex2(2.88539008f * c)), 1.0f);
      h = sox * th;                                                // o * tanh(c)

      if (lane < HH) hs[(size_t)t * HH + lane] = h;
    }
  }

  if (lane < HH) {
    dout[TT + lane] = h;        // hT
    dout[TT + HH + lane] = c;   // cT
  }
}

// ---------------- Phase 3: output projection ---------------------------
__global__ __launch_bounds__(256)
void proj(const float* __restrict__ hs,    // (T, 20)
          const float* __restrict__ Wout,  // (1, 20)
          const float* __restrict__ bout,  // (1)
          float* __restrict__ out)         // (T)
{
  const int t = blockIdx.x * 256 + threadIdx.x;
  const float4* hp = (const float4*)(hs + (size_t)t * HH);  // 80B rows: 16B aligned
  float acc = bout[0];
#pragma unroll
  for (int q = 0; q < 5; ++q) {
    float4 hv = hp[q];
    float4 wv = *(const float4*)&Wout[q * 4];
    acc = fmaf(hv.x, wv.x, acc);
    acc = fmaf(hv.y, wv.y, acc);
    acc = fmaf(hv.z, wv.z, acc);
    acc = fmaf(hv.w, wv.w, acc);
  }
  out[t] = acc;
}

extern "C" void kernel_launch(void* const* d_in, const int* in_sizes, int n_in,
                              void* d_out, int out_size, void* d_ws, size_t ws_size,
                              hipStream_t stream) {
  const float* x    = (const float*)d_in[0];
  const float* h0   = (const float*)d_in[1];
  const float* c0   = (const float*)d_in[2];
  const float* Wih  = (const float*)d_in[3];
  const float* Whh  = (const float*)d_in[4];
  const float* bih  = (const float*)d_in[5];
  const float* bhh  = (const float*)d_in[6];
  const float* Wout = (const float*)d_in[7];
  const float* bout = (const float*)d_in[8];
  float* out = (float*)d_out;

  float* xg = (float*)d_ws;                       // (T+16) x 80
  float* hs = xg + (size_t)(TT + 16) * 80;        // T x 20

  xg_gemm<<<dim3(TT / 64), dim3(256), 0, stream>>>(x, Wih, bih, bhh, xg);
  lstm_scan<<<dim3(1), dim3(64), 0, stream>>>(xg, Whh, h0, c0, hs, out);
  proj<<<dim3(TT / 256), dim3(256), 0, stream>>>(hs, Wout, bout, out);
}